// Round 1
// 494.399 us; speedup vs baseline: 1.0755x; 1.0755x over previous
//
#include <hip/hip_runtime.h>
#include <hip/hip_bf16.h>

// Correlation layer: out[b, i*41+j, y, x] = (1/576) * sum_c in1[b,c,y,x]*in2[b,c,y-dy,x-dx]
// dx = 2i-20, dy = 2j-20 (i = m/41, j = m%41), zero padding outside.
// b=4, c=64, h=96, w=160, D=41. Output 4*1681*96*160 fp32 = 413 MB -> write-bound.
// Strategy: bf16 NHWC staging in ws, then per-(b,y,j) block computes the banded
// Gram matrix between in1 row y and in2 row y2=y+20-2j with mfma_f32_16x16x32_bf16,
// exploiting even-dx parity (even/odd x-tiles), LDS diag-extract, coalesced stores.
//
// R1 changes vs baseline (535 us):
//  - Grid order swapped to (y, j, b): y is now fastest-varying, so concurrently
//    resident blocks write ADJACENT 640B y-segments of the same output channels
//    (previously j-fastest sprayed 640B chunks across the whole 413MB span).
//  - Output stores are nontemporal: output is write-once; keep the 413MB write
//    stream from evicting the 15.7MB bf16 workspace out of L2.
//  - to_nhwc builds packed u32 words directly (no ushort[64] array type-punned
//    to uint4 -> no SROA/scratch risk).

#define B_ 4
#define C_ 64
#define H_ 96
#define W_ 160
#define DD 41
#define HW_ (H_*W_)
#define RS 72            // s2 LDS row stride (64 ch + 8 pad) -> 144 B rows, 16B-aligned
#define GS 161           // Gd row stride (floats): 161 % 32 == 1 -> conflict-free scatter

typedef __bf16 bf16x8 __attribute__((ext_vector_type(8)));
typedef float  f32x4  __attribute__((ext_vector_type(4)));
typedef unsigned int u32x4 __attribute__((ext_vector_type(4)));

// ---------------- Pass 1: NCHW fp32 -> NHWC bf16 ----------------
__global__ void to_nhwc(const float* __restrict__ s1, const float* __restrict__ s2,
                        ushort* __restrict__ d1, ushort* __restrict__ d2) {
    int p = blockIdx.x * 256 + threadIdx.x;            // pixel id in [0, B*H*W)
    const float* src = blockIdx.y ? s2 : s1;
    ushort* dst = blockIdx.y ? d2 : d1;
    int b = p / HW_;
    int rem = p - b * HW_;
    const float* sp = src + (size_t)b * (C_ * HW_) + rem;
    unsigned words[32];
#pragma unroll
    for (int k = 0; k < 32; ++k) {
        union { float f; unsigned u; } lo, hi;
        lo.f = sp[(size_t)(2 * k) * HW_];              // coalesced across lanes
        hi.f = sp[(size_t)(2 * k + 1) * HW_];
        unsigned rl = (lo.u + 0x7FFFu + ((lo.u >> 16) & 1u)) >> 16;         // RNE
        unsigned rh = (hi.u + 0x7FFFu + ((hi.u >> 16) & 1u)) & 0xFFFF0000u; // RNE
        words[k] = rl | rh;
    }
    u32x4* dp = (u32x4*)(dst + (size_t)p * C_);
#pragma unroll
    for (int k = 0; k < 8; ++k) {
        u32x4 v = { words[4 * k], words[4 * k + 1], words[4 * k + 2], words[4 * k + 3] };
        dp[k] = v;
    }
}

// ---------------- Pass 2: correlation ----------------
__global__ __launch_bounds__(256) void corr_kernel(const ushort* __restrict__ in1w,
                                                   const ushort* __restrict__ in2w,
                                                   float* __restrict__ out) {
    __shared__ ushort s2[2 * 80 * RS];    // in2 row, parity-split: [par][u>>1][72]
    __shared__ float  gd[DD * GS];        // Gd[i][x], banded Gram, stride 161

    const int y   = blockIdx.x;           // y fastest: concurrent blocks write adjacent rows
    const int j   = blockIdx.y;           // dy index
    const int b   = blockIdx.z;
    const int tid = threadIdx.x;
    const int lane = tid & 63;
    const int w    = tid >> 6;            // wave id 0..3
    const int y2 = y + 20 - 2 * j;
    const bool valid_row = (y2 >= 0) && (y2 < H_);

    if (valid_row) {
        // ---- stage in2 row y2 (160 px * 64 ch bf16 = 20 KB) into parity-split LDS
        const uint4* src = (const uint4*)(in2w + (size_t)((b * H_ + y2) * W_) * C_);
#pragma unroll
        for (int it = 0; it < 5; ++it) {
            int cidx = it * 256 + tid;            // 1280 chunks of 16 B
            int u  = cidx >> 3;
            int co = (cidx & 7) * 8;
            uint4 v = src[cidx];                  // fully coalesced
            *(uint4*)&s2[((u & 1) * 80 + (u >> 1)) * RS + co] = v;
        }
        __syncthreads();

        // ---- MFMA Gram tiles: 40 (Mtile,Ntile) products, 10 per wave
        const int quad = lane >> 4;
        const int l15  = lane & 15;
        const ushort* a_base = in1w + (size_t)((b * H_ + y) * W_) * C_;
        for (int t = 0; t < 10; ++t) {
            int p  = w * 10 + t;
            int mi = p >> 2;                      // M-tile 0..9 (0-4 even x, 5-9 odd x)
            int nt = p & 3;                       // N-tile (u) 0..3
            int par = (mi >= 5) ? 1 : 0;
            int x0  = (mi - 5 * par) * 32;        // 0,32,64,96,128
            // A fragment: A[m=lane&15][k=quad*8+jj], x = x0+par+2*m
            int xa = x0 + par + 2 * l15;
            const bf16x8* aptr = (const bf16x8*)(const void*)(a_base + xa * C_ + quad * 8);
            bf16x8 a0 = aptr[0];                  // k 0..31
            bf16x8 a1 = aptr[4];                  // k 32..63
            // B fragment: B[k=quad*8+jj][n=lane&15], u = u0 + 2*n (same parity as x)
            int u0 = x0 + par - 60 + 32 * nt;
            int u  = u0 + 2 * l15;
            bf16x8 b0 = {}, b1 = {};
            if (u >= 0 && u < W_) {
                const bf16x8* bptr =
                    (const bf16x8*)(const void*)&s2[((u & 1) * 80 + (u >> 1)) * RS + quad * 8];
                b0 = bptr[0];
                b1 = bptr[4];
            }
            f32x4 acc = {};
            acc = __builtin_amdgcn_mfma_f32_16x16x32_bf16(a0, b0, acc, 0, 0, 0);
            acc = __builtin_amdgcn_mfma_f32_16x16x32_bf16(a1, b1, acc, 0, 0, 0);
            // ---- scatter band: C/D layout col(n)=lane&15, row(m)=quad*4+reg
            // dx = x-u = 2(mx-nu) + 60 - 32*nt ; i = (dx+20)/2 = mx - nu - 16*nt + 40
#pragma unroll
            for (int r = 0; r < 4; ++r) {
                int mx = quad * 4 + r;
                int i  = mx - l15 - 16 * nt + 40;
                if (i >= 0 && i <= 40) {
                    int x = x0 + par + 2 * mx;
                    gd[i * GS + x] = acc[r];      // each (i,x) written exactly once
                }
            }
        }
        __syncthreads();
    }

    // ---- output pass: out[b, i*41+j, y, 0..159], fully coalesced 640 B rows
    const float scale = 1.0f / 576.0f;
    for (int i = w; i < DD; i += 4) {
        float* op = out + ((size_t)(b * (DD * DD) + i * DD + j) * H_ + y) * W_;
        if (valid_row) {
            __builtin_nontemporal_store(gd[i * GS + lane] * scale, op + lane);
            __builtin_nontemporal_store(gd[i * GS + lane + 64] * scale, op + lane + 64);
            if (lane < 32)
                __builtin_nontemporal_store(gd[i * GS + lane + 128] * scale, op + lane + 128);
        } else {
            __builtin_nontemporal_store(0.0f, op + lane);
            __builtin_nontemporal_store(0.0f, op + lane + 64);
            if (lane < 32)
                __builtin_nontemporal_store(0.0f, op + lane + 128);
        }
    }
}

extern "C" void kernel_launch(void* const* d_in, const int* in_sizes, int n_in,
                              void* d_out, int out_size, void* d_ws, size_t ws_size,
                              hipStream_t stream) {
    const float* in1 = (const float*)d_in[0];
    const float* in2 = (const float*)d_in[1];
    float* out = (float*)d_out;
    ushort* w1 = (ushort*)d_ws;                      // 4*96*160*64 bf16 = 7.86 MB
    ushort* w2 = w1 + (size_t)B_ * H_ * W_ * C_;     // second tensor
    // Pass 1: transpose+cast both inputs (B*H*W = 61440 pixels, 240 blocks x 2)
    to_nhwc<<<dim3((B_ * HW_) / 256, 2), 256, 0, stream>>>(in1, in2, w1, w2);
    // Pass 2: one block per (y, j, b) -- y fastest for write locality
    corr_kernel<<<dim3(H_, DD, B_), 256, 0, stream>>>(w1, w2, out);
}